// Round 1
// baseline (32.763 us; speedup 1.0000x reference)
//
#include <hip/hip_runtime.h>
#include <math.h>

namespace {

constexpr float P_BF = 0.02f;
constexpr float P_DP = 0.03f;

struct C2f { float x, y; };

__device__ inline C2f cmulf(C2f a, C2f b){ return C2f{a.x*b.x - a.y*b.y, a.x*b.y + a.y*b.x}; }
__device__ inline C2f caddf(C2f a, C2f b){ return C2f{a.x+b.x, a.y+b.y}; }
__device__ inline C2f cconjf(C2f a){ return C2f{a.x, -a.y}; }
__device__ inline C2f cscalef(C2f a, float s){ return C2f{a.x*s, a.y*s}; }

// insert a 0 bit at position p of a 4-bit value -> 5-bit value
__device__ inline int ins0(int v, int p){ return ((v>>p)<<(p+1)) | (v & ((1<<p)-1)); }

// PennyLane Rot(phi,theta,omega) = RZ(omega) RY(theta) RZ(phi)
__device__ inline void rot_u(float phi, float theta, float omega, C2f U[2][2]){
  float c = cosf(0.5f*theta), s = sinf(0.5f*theta);
  float ap = -0.5f*(phi+omega), am = -0.5f*(phi-omega);
  C2f ep{cosf(ap), sinf(ap)};
  C2f em{cosf(am), sinf(am)};
  U[0][0] = cscalef(ep, c);
  C2f cem = cconjf(em);
  U[0][1] = C2f{-cem.x*s, -cem.y*s};
  U[1][0] = cscalef(em, s);
  U[1][1] = cscalef(cconjf(ep), c);
}

__device__ inline void mul4r(const float* A, const float* B, float* C){
  for (int r0 = 0; r0 < 4; ++r0)
    for (int c0 = 0; c0 < 4; ++c0){
      float acc = 0.f;
      for (int m = 0; m < 4; ++m) acc += A[r0*4+m]*B[m*4+c0];
      C[r0*4+c0] = acc;
    }
}

// M = S_depol * S_bitflip  (real 4x4 superop in (ket-bit,bra-bit) basis, row=(k*2+b))
__device__ inline void build_m1(float* M){
  const float pb = P_BF, pd = P_DP;
  float Sbf[16] = {1.f-pb, 0.f,    0.f,    pb,
                   0.f,    1.f-pb, pb,     0.f,
                   0.f,    pb,     1.f-pb, 0.f,
                   pb,     0.f,    0.f,    1.f-pb};
  float Sdp[16] = {1.f-2.f*pd/3.f, 0.f,            0.f,            2.f*pd/3.f,
                   0.f,            1.f-4.f*pd/3.f, 0.f,            0.f,
                   0.f,            0.f,            1.f-4.f*pd/3.f, 0.f,
                   2.f*pd/3.f,     0.f,            0.f,            1.f-2.f*pd/3.f};
  mul4r(Sdp, Sbf, M);
}

// apply 4x4 superop S to qubit slot s of 5-qubit rho (1024 C2f in LDS)
// slot s <-> bit position (4-s) of both ket (index>>5) and bra (index&31)
__device__ inline void apply_quad(C2f* rho, const C2f* S, int s, int t){
  const int p = 4 - s;
  const int bstep = 1 << p;
  const int kstep = 32 << p;
  for (int qq = 0; qq < 4; ++qq){
    const int q = t*4 + qq;          // 256 quads, 4 per thread
    const int kq = q >> 4, bq = q & 15;
    const int base = ins0(kq, p)*32 + ins0(bq, p);
    C2f v0 = rho[base];
    C2f v1 = rho[base + bstep];
    C2f v2 = rho[base + kstep];
    C2f v3 = rho[base + kstep + bstep];
    C2f n0 = caddf(caddf(cmulf(S[0],  v0), cmulf(S[1],  v1)), caddf(cmulf(S[2],  v2), cmulf(S[3],  v3)));
    C2f n1 = caddf(caddf(cmulf(S[4],  v0), cmulf(S[5],  v1)), caddf(cmulf(S[6],  v2), cmulf(S[7],  v3)));
    C2f n2 = caddf(caddf(cmulf(S[8],  v0), cmulf(S[9],  v1)), caddf(cmulf(S[10], v2), cmulf(S[11], v3)));
    C2f n3 = caddf(caddf(cmulf(S[12], v0), cmulf(S[13], v1)), caddf(cmulf(S[14], v2), cmulf(S[15], v3)));
    rho[base] = n0;
    rho[base + bstep] = n1;
    rho[base + kstep] = n2;
    rho[base + kstep + bstep] = n3;
  }
}

__global__ __launch_bounds__(64) void pqc_kernel(const float* __restrict__ xg,
                                                 const float* __restrict__ wgt,
                                                 float* __restrict__ outg)
{
  __shared__ C2f rho[1024];       // 32x32 density matrix, index = ket*32+bra
  __shared__ C2f sup[3][5][16];   // per-(block, window-slot) composed superop
  __shared__ C2f n7s[16];         // depol*bitflip superop (inter-block wire-7 noise)

  const int task = (int)blockIdx.x;
  const int r  = task >> 3;   // batch
  const int iw = task & 7;    // measured wire; window wires = iw-2 .. iw+2 (slot 2 = iw)
  const int t  = (int)threadIdx.x;

  // ---- prologue: build superops (15 threads) + noise7 (thread 15) ----
  if (t < 15){
    const int b = t / 5, s = t % 5;
    const int wi = iw - 2 + s;
    if (wi >= 0 && wi < 8){
      float phi1 = xg[r*24 + 3*wi + 0];
      float th1  = xg[r*24 + 3*wi + 1];
      float om1  = xg[r*24 + 3*wi + 2];
      const float* wp = wgt + (b*8 + wi)*3;
      C2f U1[2][2], U2[2][2], U[2][2];
      rot_u(phi1, th1, om1, U1);       // data rot (applied first)
      rot_u(wp[0], wp[1], wp[2], U2);  // weight rot (applied second)
      for (int k = 0; k < 2; ++k)
        for (int j = 0; j < 2; ++j)
          U[k][j] = caddf(cmulf(U2[k][0], U1[0][j]), cmulf(U2[k][1], U1[1][j]));
      // unitary superop: S[(k,b),(k',b')] = U[k][k'] * conj(U[b][b'])
      C2f SU[16];
      for (int k = 0; k < 2; ++k)
        for (int b2 = 0; b2 < 2; ++b2)
          for (int k2 = 0; k2 < 2; ++k2)
            for (int b3 = 0; b3 < 2; ++b3)
              SU[(k*2+b2)*4 + (k2*2+b3)] = cmulf(U[k][k2], cconjf(U[b2][b3]));
      // noise: amp_damp(g) ∘ depol ∘ bitflip  (g = sigmoid(x3[0]), block-independent)
      float M1[16]; build_m1(M1);
      float g  = 1.f/(1.f + expf(-phi1));
      float rr = sqrtf(fmaxf(1.f - g, 0.f));
      float Sad[16] = {1.f, 0.f, 0.f, g,
                       0.f, rr,  0.f, 0.f,
                       0.f, 0.f, rr,  0.f,
                       0.f, 0.f, 0.f, 1.f-g};
      float N[16]; mul4r(Sad, M1, N);
      for (int r0 = 0; r0 < 4; ++r0)
        for (int c0 = 0; c0 < 4; ++c0){
          C2f acc{0.f, 0.f};
          for (int m = 0; m < 4; ++m)
            acc = caddf(acc, cscalef(SU[m*4+c0], N[r0*4+m]));
          sup[b][s][r0*4+c0] = acc;
        }
    }
  } else if (t == 15){
    float M1[16]; build_m1(M1);
    for (int e = 0; e < 16; ++e) n7s[e] = C2f{M1[e], 0.f};
  }

  // init rho = |00000><00000|
  for (int e = 0; e < 16; ++e) rho[t*16+e] = C2f{0.f, 0.f};
  if (t == 0) rho[0] = C2f{1.f, 0.f};
  __syncthreads();

  // ---- main evolution ----
  for (int b = 0; b < 3; ++b){
    for (int s = 0; s < 5; ++s){
      const int wi = iw - 2 + s;
      if (wi >= 0 && wi < 8){
        apply_quad(rho, sup[b][s], s, t);
      }
      __syncthreads();
    }
    if (b < 2){
      // CZ chain: keep pairs (w,w+1) fully inside window, 0 <= w <= 6
      for (int e = 0; e < 16; ++e){
        int idx = t*16 + e;
        int k  = idx >> 5, br = idx & 31;
        int par = 0;
        for (int s = 0; s < 4; ++s){
          int wi = iw - 2 + s;
          if (wi >= 0 && wi <= 6){
            int p1 = 4 - s, p2 = 3 - s;
            par ^= (((k>>p1)&(k>>p2)) ^ ((br>>p1)&(br>>p2))) & 1;
          }
        }
        if (par){ rho[idx].x = -rho[idx].x; rho[idx].y = -rho[idx].y; }
      }
      __syncthreads();
      // trailing noise on wire 7 (present in window iff iw >= 5; slot = 9-iw)
      if (iw >= 5){
        apply_quad(rho, n7s, 9 - iw, t);
      }
      __syncthreads();
    }
  }

  // ---- <Z_iw> = sum over diagonal with sign from slot-2 ket bit (bit 2) ----
  float val = 0.f;
  if (t < 32){
    C2f d = rho[t*32 + t];
    val = ((t>>2)&1) ? -d.x : d.x;
  }
  #pragma unroll
  for (int off = 32; off >= 1; off >>= 1) val += __shfl_xor(val, off, 64);
  if (t == 0) outg[r*8 + iw] = val;
}

} // namespace

extern "C" void kernel_launch(void* const* d_in, const int* in_sizes, int n_in,
                              void* d_out, int out_size, void* d_ws, size_t ws_size,
                              hipStream_t stream) {
  (void)in_sizes; (void)n_in; (void)d_ws; (void)ws_size; (void)out_size;
  const float* x = (const float*)d_in[0];   // [64, 24]
  const float* w = (const float*)d_in[1];   // [3, 8, 3]
  float* out = (float*)d_out;               // [64, 8]
  pqc_kernel<<<dim3(512), dim3(64), 0, stream>>>(x, w, out);
}

// Round 2
// 12.012 us; speedup vs baseline: 2.7276x; 2.7276x over previous
//
#include <hip/hip_runtime.h>
#include <math.h>

namespace {

constexpr float P_BF = 0.02f;
constexpr float P_DP = 0.03f;

// Bloch-sphere rotation of Rot(phi,theta,omega) = RZ(omega) RY(theta) RZ(phi):
// R = Rz(omega) * Ry(theta) * Rz(phi), closed-form ZYZ Euler matrix.
__device__ inline void rot3(float ph, float th, float om, float R[3][3]){
  float sp,cp,st,ct,so,co;
  sincosf(ph,&sp,&cp); sincosf(th,&st,&ct); sincosf(om,&so,&co);
  R[0][0]= co*ct*cp - so*sp; R[0][1]= -co*ct*sp - so*cp; R[0][2]= co*st;
  R[1][0]= so*ct*cp + co*sp; R[1][1]= -so*ct*sp + co*cp; R[1][2]= so*st;
  R[2][0]= -st*cp;           R[2][1]=  st*sp;            R[2][2]= ct;
}

// Full 4x4 Pauli transfer matrix of one wire step:
//   ampdamp(sigmoid(x0)) ∘ depol ∘ bitflip ∘ Rot(w3) ∘ Rot(x3)
// Basis order (I,X,Y,Z); M[a][b] = (1/2) tr(P_a E(P_b)).
__device__ inline void wire_ptm(const float* __restrict__ x3,
                                const float* __restrict__ w3,
                                float M[4][4]){
  float Rx[3][3], Rw[3][3], R[3][3];
  rot3(x3[0],x3[1],x3[2],Rx);
  rot3(w3[0],w3[1],w3[2],Rw);
  #pragma unroll
  for (int i=0;i<3;++i)
    #pragma unroll
    for (int j=0;j<3;++j)
      R[i][j] = Rw[i][0]*Rx[0][j] + Rw[i][1]*Rx[1][j] + Rw[i][2]*Rx[2][j];
  float g  = 1.f/(1.f+expf(-x3[0]));
  float sq = sqrtf(fmaxf(1.f-g,0.f));
  const float c = 1.f - 4.f*P_DP/3.f;   // depol: X,Y,Z scale
  const float b = 1.f - 2.f*P_BF;       // bitflip: Y,Z scale
  M[0][0]=1.f; M[0][1]=0.f; M[0][2]=0.f; M[0][3]=0.f;
  M[1][0]=0.f; M[2][0]=0.f; M[3][0]=g;
  #pragma unroll
  for (int j=0;j<3;++j){
    M[1][j+1] = sq*c*R[0][j];
    M[2][j+1] = sq*c*b*R[1][j];
    M[3][j+1] = (1.f-g)*c*b*R[2][j];
  }
}

// One thread per (batch r, wire iw). Heisenberg-evolve Z_iw backward:
//   out = e_Z^T T2 N7 CZL T1 N7 CZL (T0 r0)
// Support: {iw} -> {iw-1..iw+1} -> contraction over {iw-2..iw+2}.
__global__ __launch_bounds__(64) void pqc_ptm(const float* __restrict__ xg,
                                              const float* __restrict__ wgt,
                                              float* __restrict__ outg){
  const int tid = (int)blockIdx.x*64 + (int)threadIdx.x;   // 0..511
  const int r = tid>>3, iw = tid&7;
  const float* xr = xg + r*24;

  const float cdp = 1.f - 4.f*P_DP/3.f;
  const float bbf = 1.f - 2.f*P_BF;
  const float nd1 = cdp, nd2 = cdp*bbf, nd3 = cdp*bbf;  // depol∘bitflip diag (I term = 1)

  const bool has_l = iw>=1, has_r = iw<=6;
  const bool cz_s0 = iw>=2, cz_s1 = has_l, cz_s2 = has_r, cz_s3 = iw<=5;
  const int wl  = has_l ? iw-1 : 0;   // clamped neighbor wire indices (flags gate semantics)
  const int wr  = has_r ? iw+1 : 7;
  const int wll = cz_s0 ? iw-2 : 0;
  const int wrr = cz_s3 ? iw+2 : 7;

  float M[4][4];

  // ---- a1 = Z-row of block-2 PTM on wire iw; then inter-block noise (blk1 trailing) if iw==7
  wire_ptm(xr+3*iw, wgt+(16+iw)*3, M);
  float a1[4] = {M[3][0], M[3][1], M[3][2], M[3][3]};
  if (iw==7){ a1[1]*=nd1; a1[2]*=nd2; a1[3]*=nd3; }

  // ---- block-1: center wire full PTM; neighbors only their Z-rows (they receive I or Z from CZL_b)
  float Mb[4][4];
  wire_ptm(xr+3*iw, wgt+(8+iw)*3, Mb);
  wire_ptm(xr+3*wl, wgt+(8+wl)*3, M);
  float L[4];
  #pragma unroll
  for (int x=0;x<4;++x) L[x] = has_l ? M[3][x] : (x==0?1.f:0.f);
  wire_ptm(xr+3*wr, wgt+(8+wr)*3, M);
  float Rv[4];
  #pragma unroll
  for (int z=0;z<4;++z) Rv[z] = has_r ? M[3][z] : (z==0?1.f:0.f);

  // a4[x][y][z] = dx0*dz0*A[y] + L[x]*B[y]*Rv[z]
  float A[4], B[4];
  #pragma unroll
  for (int y=0;y<4;++y){
    A[y] = a1[0]*Mb[0][y] + a1[3]*Mb[3][y];
    B[y] = a1[1]*Mb[1][y] + a1[2]*Mb[2][y];
  }
  B[0] = 0.f;  // Mb[1][0]=Mb[2][0]=0 structurally

  // ---- inter-block noise (blk0 trailing) on wire 7, support {iw-1,iw,iw+1}
  if (iw==7){
    A[1]*=nd1; A[2]*=nd2; A[3]*=nd3;
    B[1]*=nd1; B[2]*=nd2; B[3]*=nd3;
  }
  if (iw==6){
    Rv[1]*=nd1; Rv[2]*=nd2; Rv[3]*=nd3;
  }

  // ---- block-0 forward-evolved initial vectors m_j = M_j^(0) (e_I + e_Z)
  float m1[4], m2[4], m3[4], m0z, m4z;
  wire_ptm(xr+3*iw, wgt+iw*3, M);
  #pragma unroll
  for (int q=0;q<4;++q) m2[q] = M[q][0]+M[q][3];
  wire_ptm(xr+3*wl, wgt+wl*3, M);
  #pragma unroll
  for (int q=0;q<4;++q) m1[q] = M[q][0]+M[q][3];  // m1[0]==1 always
  wire_ptm(xr+3*wr, wgt+wr*3, M);
  #pragma unroll
  for (int q=0;q<4;++q) m3[q] = M[q][0]+M[q][3];
  wire_ptm(xr+3*wll, wgt+wll*3, M);
  m0z = M[3][0]+M[3][3];
  wire_ptm(xr+3*wrr, wgt+wrr*3, M);
  m4z = M[3][0]+M[3][3];

  // ---- final CZ layer (blk0 trailing) as signed basis map + contraction
  // CZ(p,q): p' = p^3 if q in {X,Y}; q' = q^3 if p in {X,Y}; sign -1 iff both in {X,Y} and p!=q.
  float out = 0.f;

  // Term1: a4 part dx0*dz0*A[y]  (slots 1,3 get I or Z only)
  #pragma unroll
  for (int p2=0;p2<4;++p2){
    float t = A[p2]*m2[p2];
    if (p2==1||p2==2){
      t *= cz_s1 ? m1[3] : 1.f;
      t *= cz_s2 ? m3[3] : 1.f;
    }
    out += t;
  }

  // Term2: a4 part L[p1]*B[p2]*Rv[p3]
  #pragma unroll
  for (int p1=0;p1<4;++p1){
    const bool in1 = (p1==1)||(p1==2);
    const float v0 = (cz_s0 && in1) ? m0z : 1.f;
    const float lp = L[p1]*v0;
    #pragma unroll
    for (int p2=1;p2<4;++p2){
      const bool in2 = (p2==1)||(p2==2);
      const float q1v  = (cz_s1 && in2) ? m1[p1^3] : m1[p1];
      const bool  f1   = cz_s1 && in1;                       // CZ(s1,s2) flips slot2
      const float sgn1 = (cz_s1 && in1 && in2 && (p1!=p2)) ? -1.f : 1.f;
      const float base = lp * B[p2] * q1v * sgn1;
      #pragma unroll
      for (int p3=0;p3<4;++p3){
        const bool in3 = (p3==1)||(p3==2);
        const float v4 = (cz_s3 && in3) ? m4z : 1.f;
        const bool  f2 = cz_s2 && in3;                       // CZ(s2,s3) flips slot2
        const float q2v = (f1!=f2) ? m2[p2^3] : m2[p2];
        const float q3v = (cz_s2 && in2) ? m3[p3^3] : m3[p3];
        const bool  neq = f1 ? ((p2^3)!=p3) : (p2!=p3);
        const float sgn2 = (cz_s2 && in2 && in3 && neq) ? -1.f : 1.f;
        out += base * Rv[p3] * v4 * q2v * q3v * sgn2;
      }
    }
  }

  outg[r*8+iw] = out;
}

} // namespace

extern "C" void kernel_launch(void* const* d_in, const int* in_sizes, int n_in,
                              void* d_out, int out_size, void* d_ws, size_t ws_size,
                              hipStream_t stream) {
  (void)in_sizes; (void)n_in; (void)d_ws; (void)ws_size; (void)out_size;
  const float* x = (const float*)d_in[0];   // [64, 24]
  const float* w = (const float*)d_in[1];   // [3, 8, 3]
  float* out = (float*)d_out;               // [64, 8]
  pqc_ptm<<<dim3(8), dim3(64), 0, stream>>>(x, w, out);
}

// Round 3
// 9.631 us; speedup vs baseline: 3.4019x; 1.2472x over previous
//
#include <hip/hip_runtime.h>
#include <math.h>

namespace {

constexpr float P_BF = 0.02f;
constexpr float P_DP = 0.03f;

// Bloch rotation of Rot(phi,theta,omega) = RZ(omega) RY(theta) RZ(phi)
__device__ inline void rot3(float ph, float th, float om, float R[3][3]){
  float sp,cp,st,ct,so,co;
  sincosf(ph,&sp,&cp); sincosf(th,&st,&ct); sincosf(om,&so,&co);
  R[0][0]= co*ct*cp - so*sp; R[0][1]= -co*ct*sp - so*cp; R[0][2]= co*st;
  R[1][0]= so*ct*cp + co*sp; R[1][1]= -so*ct*sp + co*cp; R[1][2]= so*st;
  R[2][0]= -st*cp;           R[2][1]=  st*sp;            R[2][2]= ct;
}

// Full 4x4 PTM of one wire step: ampdamp(sigmoid(x0)) ∘ depol ∘ bitflip ∘ Rot(w3) ∘ Rot(x3)
__device__ inline void wire_ptm(const float* __restrict__ x3,
                                const float* __restrict__ w3,
                                float M[4][4]){
  float Rx[3][3], Rw[3][3], R[3][3];
  rot3(x3[0],x3[1],x3[2],Rx);
  rot3(w3[0],w3[1],w3[2],Rw);
  #pragma unroll
  for (int i=0;i<3;++i)
    #pragma unroll
    for (int j=0;j<3;++j)
      R[i][j] = Rw[i][0]*Rx[0][j] + Rw[i][1]*Rx[1][j] + Rw[i][2]*Rx[2][j];
  float g  = 1.f/(1.f+expf(-x3[0]));
  float sq = sqrtf(fmaxf(1.f-g,0.f));
  const float c = 1.f - 4.f*P_DP/3.f;
  const float b = 1.f - 2.f*P_BF;
  M[0][0]=1.f; M[0][1]=0.f; M[0][2]=0.f; M[0][3]=0.f;
  M[1][0]=0.f; M[2][0]=0.f; M[3][0]=g;
  #pragma unroll
  for (int j=0;j<3;++j){
    M[1][j+1] = sq*c*R[0][j];
    M[2][j+1] = sq*c*b*R[1][j];
    M[3][j+1] = (1.f-g)*c*b*R[2][j];
  }
}

// One block per batch element. Phase 1: lanes 0..23 build the 24 PTMs (blk,wire)
// into LDS. Phase 2: lanes 0..7 contract the light-cone for Z_iw.
__global__ __launch_bounds__(64) void pqc_ptm2(const float* __restrict__ xg,
                                               const float* __restrict__ wgt,
                                               float* __restrict__ outg){
  __shared__ float Ms[3][8][4][4];
  const int r = (int)blockIdx.x;
  const int t = (int)threadIdx.x;
  const float* xr = xg + r*24;

  if (t < 24){
    const int blk = t>>3, wire = t&7;
    float M[4][4];
    wire_ptm(xr + 3*wire, wgt + (blk*8 + wire)*3, M);
    #pragma unroll
    for (int a=0;a<4;++a)
      #pragma unroll
      for (int b=0;b<4;++b) Ms[blk][wire][a][b] = M[a][b];
  }
  __syncthreads();

  if (t < 8){
    const int iw = t;
    const float cdp = 1.f - 4.f*P_DP/3.f;
    const float bbf = 1.f - 2.f*P_BF;
    const float nd1 = cdp, nd2 = cdp*bbf, nd3 = cdp*bbf;

    const bool has_l = iw>=1, has_r = iw<=6;
    const bool cz_s0 = iw>=2, cz_s1 = has_l, cz_s2 = has_r, cz_s3 = iw<=5;
    const int wl  = has_l ? iw-1 : 0;
    const int wr  = has_r ? iw+1 : 7;
    const int wll = cz_s0 ? iw-2 : 0;
    const int wrr = cz_s3 ? iw+2 : 7;

    // a1 = Z-row of block-2 PTM on wire iw (+ inter-block noise if iw==7)
    float a1[4];
    #pragma unroll
    for (int q=0;q<4;++q) a1[q] = Ms[2][iw][3][q];
    if (iw==7){ a1[1]*=nd1; a1[2]*=nd2; a1[3]*=nd3; }

    // block-1: center full PTM rows via A/B; neighbors' Z-rows
    float L[4], Rv[4];
    #pragma unroll
    for (int q=0;q<4;++q){
      L[q]  = has_l ? Ms[1][wl][3][q] : (q==0?1.f:0.f);
      Rv[q] = has_r ? Ms[1][wr][3][q] : (q==0?1.f:0.f);
    }
    float A[4], B[4];
    #pragma unroll
    for (int y=0;y<4;++y){
      A[y] = a1[0]*Ms[1][iw][0][y] + a1[3]*Ms[1][iw][3][y];
      B[y] = a1[1]*Ms[1][iw][1][y] + a1[2]*Ms[1][iw][2][y];
    }
    B[0] = 0.f;

    if (iw==7){
      A[1]*=nd1; A[2]*=nd2; A[3]*=nd3;
      B[1]*=nd1; B[2]*=nd2; B[3]*=nd3;
    }
    if (iw==6){ Rv[1]*=nd1; Rv[2]*=nd2; Rv[3]*=nd3; }

    // block-0 forward vectors m_j = M_j^(0)(e_I + e_Z)
    float m1[4], m2[4], m3[4];
    #pragma unroll
    for (int q=0;q<4;++q){
      m2[q] = Ms[0][iw][q][0] + Ms[0][iw][q][3];
      m1[q] = Ms[0][wl][q][0] + Ms[0][wl][q][3];
      m3[q] = Ms[0][wr][q][0] + Ms[0][wr][q][3];
    }
    const float m0z = Ms[0][wll][3][0] + Ms[0][wll][3][3];
    const float m4z = Ms[0][wrr][3][0] + Ms[0][wrr][3][3];

    float out = 0.f;

    // Term1: separable part dx0*dz0*A[y]
    #pragma unroll
    for (int p2=0;p2<4;++p2){
      float tv = A[p2]*m2[p2];
      if (p2==1||p2==2){
        tv *= cz_s1 ? m1[3] : 1.f;
        tv *= cz_s2 ? m3[3] : 1.f;
      }
      out += tv;
    }

    // Term2: L[p1]*B[p2]*Rv[p3] with CZ signed basis maps
    #pragma unroll
    for (int p1=0;p1<4;++p1){
      const bool in1 = (p1==1)||(p1==2);
      const float v0 = (cz_s0 && in1) ? m0z : 1.f;
      const float lp = L[p1]*v0;
      #pragma unroll
      for (int p2=1;p2<4;++p2){
        const bool in2 = (p2==1)||(p2==2);
        const float q1v  = (cz_s1 && in2) ? m1[p1^3] : m1[p1];
        const bool  f1   = cz_s1 && in1;
        const float sgn1 = (cz_s1 && in1 && in2 && (p1!=p2)) ? -1.f : 1.f;
        const float base = lp * B[p2] * q1v * sgn1;
        #pragma unroll
        for (int p3=0;p3<4;++p3){
          const bool in3 = (p3==1)||(p3==2);
          const float v4 = (cz_s3 && in3) ? m4z : 1.f;
          const bool  f2 = cz_s2 && in3;
          const float q2v = (f1!=f2) ? m2[p2^3] : m2[p2];
          const float q3v = (cz_s2 && in2) ? m3[p3^3] : m3[p3];
          const bool  neq = f1 ? ((p2^3)!=p3) : (p2!=p3);
          const float sgn2 = (cz_s2 && in2 && in3 && neq) ? -1.f : 1.f;
          out += base * Rv[p3] * v4 * q2v * q3v * sgn2;
        }
      }
    }

    outg[r*8 + iw] = out;
  }
}

} // namespace

extern "C" void kernel_launch(void* const* d_in, const int* in_sizes, int n_in,
                              void* d_out, int out_size, void* d_ws, size_t ws_size,
                              hipStream_t stream) {
  (void)in_sizes; (void)n_in; (void)d_ws; (void)ws_size; (void)out_size;
  const float* x = (const float*)d_in[0];   // [64, 24]
  const float* w = (const float*)d_in[1];   // [3, 8, 3]
  float* out = (float*)d_out;               // [64, 8]
  pqc_ptm2<<<dim3(64), dim3(64), 0, stream>>>(x, w, out);
}